// Round 11
// baseline (665.814 us; speedup 1.0000x reference)
//
#include <hip/hip_runtime.h>
#include <math.h>

#define H 128
#define IN 2048
#define PROJ 64
#define BT 32768      // B*T rows of x
#define T_STEPS 512
#define BATCH 64
#define BM 128
#define BKA 64
#define BTILE 16      // batch elements per block (kernel B)
#define NBLK (BATCH / BTILE)

using f32x4  = __attribute__((ext_vector_type(4))) float;
using bfrag  = __attribute__((ext_vector_type(8))) short;     // 8 bf16
using f16x8v = __attribute__((ext_vector_type(8))) _Float16;  // 8 f16

// v_cvt_pk_bf16_f32: d.lo = bf16(lo), d.hi = bf16(hi)  (RNE)
__device__ __forceinline__ unsigned cvtpk(float lo, float hi) {
  unsigned r;
  asm("v_cvt_pk_bf16_f32 %0, %1, %2" : "=v"(r) : "v"(lo), "v"(hi));
  return r;
}

// ---------------------------------------------------------------------------
// Kernel A: xp1[BT][H] = x[BT][IN] @ W_ih1^T + (b_ih1+b_hh1), bf16 MFMA.
// UNCHANGED (~60 us, near HBM floor).
// ---------------------------------------------------------------------------
__global__ __launch_bounds__(512) void xp1_gemm(
    const float* __restrict__ x, const float* __restrict__ W,
    const float* __restrict__ b1, const float* __restrict__ b2,
    float* __restrict__ xp1) {
  __shared__ __align__(16) char As[2][BM * BKA * 2];   // 2 x 16 KB
  __shared__ __align__(16) char Bs[2][H * BKA * 2];    // 2 x 16 KB
  const int t  = threadIdx.x;
  const int m0 = blockIdx.x * BM;
  const int wv = t >> 6, l = t & 63;
  const int wm = wv >> 2;
  const int wn = wv & 3;
  const int lr = l & 15;
  const int lq = l >> 4;

  const float* xg[4];
  const float* wg[4];
  int so[4];
#pragma unroll
  for (int i = 0; i < 4; ++i) {
    int c = t + 512 * i, r = c >> 4, k4 = c & 15;
    xg[i] = x + (size_t)(m0 + r) * IN + k4 * 4;
    wg[i] = W + (size_t)r * IN + k4 * 4;
    so[i] = (r * 128 + k4 * 8) ^ ((r & 7) << 4);
  }
  int ao[2][4], bo[2][2];
#pragma unroll
  for (int kf = 0; kf < 2; ++kf) {
#pragma unroll
    for (int mf = 0; mf < 4; ++mf) {
      int r = wm * 64 + mf * 16 + lr;
      ao[kf][mf] = (r * 128 + kf * 64 + lq * 16) ^ ((r & 7) << 4);
    }
#pragma unroll
    for (int nf = 0; nf < 2; ++nf) {
      int r = wn * 32 + nf * 16 + lr;
      bo[kf][nf] = (r * 128 + kf * 64 + lq * 16) ^ ((r & 7) << 4);
    }
  }

  f32x4 acc[4][2];
#pragma unroll
  for (int mf = 0; mf < 4; ++mf)
#pragma unroll
    for (int nf = 0; nf < 2; ++nf)
#pragma unroll
      for (int j = 0; j < 4; ++j) acc[mf][nf][j] = 0.f;

  float4 xr[4], wr[4];
#pragma unroll
  for (int i = 0; i < 4; ++i) {
    xr[i] = *(const float4*)&xg[i][0];
    wr[i] = *(const float4*)&wg[i][0];
  }
#pragma unroll
  for (int i = 0; i < 4; ++i) {
    uint2 ux; ux.x = cvtpk(xr[i].x, xr[i].y); ux.y = cvtpk(xr[i].z, xr[i].w);
    *(uint2*)(As[0] + so[i]) = ux;
    uint2 uw; uw.x = cvtpk(wr[i].x, wr[i].y); uw.y = cvtpk(wr[i].z, wr[i].w);
    *(uint2*)(Bs[0] + so[i]) = uw;
  }
  __syncthreads();

  for (int tc = 0; tc < 32; ++tc) {
    const int kc = (tc + 1) * BKA;
    if (tc < 31) {
#pragma unroll
      for (int i = 0; i < 4; ++i) {
        xr[i] = *(const float4*)&xg[i][kc];
        wr[i] = *(const float4*)&wg[i][kc];
      }
    }
    const char* Ab = As[tc & 1];
    const char* Bb = Bs[tc & 1];
#pragma unroll
    for (int kf = 0; kf < 2; ++kf) {
      bfrag af[4], bf[2];
#pragma unroll
      for (int mf = 0; mf < 4; ++mf) af[mf] = *(const bfrag*)(Ab + ao[kf][mf]);
#pragma unroll
      for (int nf = 0; nf < 2; ++nf) bf[nf] = *(const bfrag*)(Bb + bo[kf][nf]);
#pragma unroll
      for (int mf = 0; mf < 4; ++mf)
#pragma unroll
        for (int nf = 0; nf < 2; ++nf)
          acc[mf][nf] = __builtin_amdgcn_mfma_f32_16x16x32_bf16(
              af[mf], bf[nf], acc[mf][nf], 0, 0, 0);
    }
    if (tc < 31) {
      char* Aw = As[(tc + 1) & 1];
      char* Bw = Bs[(tc + 1) & 1];
#pragma unroll
      for (int i = 0; i < 4; ++i) {
        uint2 ux; ux.x = cvtpk(xr[i].x, xr[i].y); ux.y = cvtpk(xr[i].z, xr[i].w);
        *(uint2*)(Aw + so[i]) = ux;
        uint2 uw; uw.x = cvtpk(wr[i].x, wr[i].y); uw.y = cvtpk(wr[i].z, wr[i].w);
        *(uint2*)(Bw + so[i]) = uw;
      }
    }
    __syncthreads();
  }

  // epilogue: C/D layout col = lane&15, row = (lane>>4)*4 + j   [m89]
#pragma unroll
  for (int nf = 0; nf < 2; ++nf) {
    int n = wn * 32 + nf * 16 + lr;
    float bias = b1[n] + b2[n];
#pragma unroll
    for (int mf = 0; mf < 4; ++mf) {
      int mr = m0 + wm * 64 + mf * 16 + lq * 4;
#pragma unroll
      for (int j = 0; j < 4; ++j)
        xp1[(size_t)(mr + j) * H + n] = acc[mf][nf][j] + bias;
    }
  }
}

// ---------------------------------------------------------------------------
// Kernel B: fused 2-layer tanh RNN, MFMA-across-batch. 4 blocks x 16 batch,
// 512 thr (8 waves; wave nw owns hidden cols [16nw,16nw+16)). Per step, each
// matvec is a 16x16x128 matmul = 4 x mfma_f32_16x16x32_f16 against per-wave
// weight fragments loaded ONCE (MFMA reads operands from AGPRs natively ->
// immune to the AGPR-shuffle tax that pinned R6-R10 at ~1700 cyc/step).
// Skewed recurrence: iter i computes h1[i] (from h1[i-1]) and h2[i-1] (from
// h1[i-1], h2[i-2]); one raw lgkm-barrier per step. h tiles f16 in LDS,
// XOR-swizzled (^(b&7)<<4) for even bank spread on b128 A-frag reads.
// A/B/C fragment layouts identical to the verified xp1_gemm usage.
// ---------------------------------------------------------------------------

// raw barrier: drain LDS ops only
__device__ __forceinline__ void bar() {
  asm volatile("s_waitcnt lgkmcnt(0)\n\ts_barrier" ::: "memory");
}

__device__ __forceinline__ float fast_tanh(float x) {
  float e = __expf(2.0f * x);
  return 1.0f - 2.0f / (e + 1.0f);
}

// one f16 store into swizzled [16][128] tile: element (b, n)
__device__ __forceinline__ void wh(char* base, int b, int n, float v) {
  *(_Float16*)(base + ((b * 256 + n * 2) ^ ((b & 7) << 4))) = (_Float16)v;
}

// weight fragment: lane holds W[n][k..k+8) as f16
__device__ __forceinline__ f16x8v ldfrag(const float* Wm, int n, int k) {
  float4 lo = *(const float4*)&Wm[n * H + k];
  float4 hi = *(const float4*)&Wm[n * H + k + 4];
  f16x8v r = {(_Float16)lo.x, (_Float16)lo.y, (_Float16)lo.z, (_Float16)lo.w,
              (_Float16)hi.x, (_Float16)hi.y, (_Float16)hi.z, (_Float16)hi.w};
  return r;
}

__global__ __launch_bounds__(512)
__attribute__((amdgpu_waves_per_eu(1, 2)))
void rnn_fused(
    const float* __restrict__ xp1,
    const float* __restrict__ W_hh1, const float* __restrict__ W_ih2,
    const float* __restrict__ W_hh2, const float* __restrict__ b_ih2,
    const float* __restrict__ b_hh2, const float* __restrict__ W_proj,
    const float* __restrict__ b_proj, const float* __restrict__ gamma,
    const float* __restrict__ beta, float* __restrict__ out) {
  __shared__ __align__(16) char h1s[2][BTILE * H * 2];   // 4 KB each, f16 swz
  __shared__ __align__(16) char h2s[2][BTILE * H * 2];
  const int t  = threadIdx.x;
  const int l  = t & 63;
  const int nw = t >> 6;         // wave id = n-tile
  const int n0 = nw * 16;
  const int lc = l & 15;         // A: batch row | B: weight row | C: col
  const int lk = l >> 4;         // k-chunk / C row-group
  const int bq = blockIdx.x * BTILE;

  const int n = n0 + lc;         // this lane's hidden column for B/C
  // --- weight fragments, loaded once: W[n][ks*32+lk*8 .. +8) ---------------
  f16x8v B1[4], B2[4], B3[4];
#pragma unroll
  for (int ks = 0; ks < 4; ++ks) {
    const int k = ks * 32 + lk * 8;
    B1[ks] = ldfrag(W_hh1, n, k);
    B2[ks] = ldfrag(W_ih2, n, k);
    B3[ks] = ldfrag(W_hh2, n, k);
  }
  const float bias2 = b_ih2[n] + b_hh2[n];

  // xp pointers for the 4 batch rows this lane's C-fragment covers
  const int rb = lk * 4;         // C row-group base (batch within tile)
  const float* xq0 = xp1 + ((size_t)(bq + rb + 0) * T_STEPS) * H + n;
  const float* xq1 = xp1 + ((size_t)(bq + rb + 1) * T_STEPS) * H + n;
  const float* xq2 = xp1 + ((size_t)(bq + rb + 2) * T_STEPS) * H + n;
  const float* xq3 = xp1 + ((size_t)(bq + rb + 3) * T_STEPS) * H + n;

  // zero h1[-1], h2[-1] (parity buffer 1); zeros are swizzle-invariant
  *(float2*)&h1s[1][8 * t] = float2{0.f, 0.f};
  *(float2*)&h2s[1][8 * t] = float2{0.f, 0.f};

  // peel i = 0: h1[0] = tanh(xp[0])
  {
    float x0 = xq0[0], x1 = xq1[0], x2 = xq2[0], x3 = xq3[0];
    wh(h1s[0], rb + 0, n, fast_tanh(x0));
    wh(h1s[0], rb + 1, n, fast_tanh(x1));
    wh(h1s[0], rb + 2, n, fast_tanh(x2));
    wh(h1s[0], rb + 3, n, fast_tanh(x3));
  }
  bar();

  // prefetch xp[1]
  float xpc0 = xq0[H], xpc1 = xq1[H], xpc2 = xq2[H], xpc3 = xq3[H];

#pragma unroll 1
  for (int i = 1; i < T_STEPS; ++i) {
    const char* h1p = h1s[(i - 1) & 1];   // h1[i-1]
    const char* h2p = h2s[i & 1];         // h2[i-2]
    char* h1w = h1s[i & 1];               // h1[i]
    char* h2w = h2s[(i - 1) & 1];         // h2[i-1]

    float nx0 = 0.f, nx1 = 0.f, nx2 = 0.f, nx3 = 0.f;
    if (i + 1 < T_STEPS) {                // prefetch xp[i+1] (full-step slack)
      size_t o = (size_t)(i + 1) * H;
      nx0 = xq0[o]; nx1 = xq1[o]; nx2 = xq2[o]; nx3 = xq3[o];
    }

    // A-fragments: lane = (batch row lc, k-chunk lk), swizzled b128 reads
    f16x8v a1[4], a2[4];
#pragma unroll
    for (int ks = 0; ks < 4; ++ks) {
      const int off = (lc * 256 + ks * 64 + lk * 16) ^ ((lc & 7) << 4);
      a1[ks] = *(const f16x8v*)(h1p + off);
      a2[ks] = *(const f16x8v*)(h2p + off);
    }

    f32x4 acc1 = {xpc0, xpc1, xpc2, xpc3};          // C init = xp[i]
    f32x4 acc2 = {bias2, bias2, bias2, bias2};      // C init = bias2[n]
    f32x4 acc3 = {0.f, 0.f, 0.f, 0.f};
#pragma unroll
    for (int ks = 0; ks < 4; ++ks) {
      acc1 = __builtin_amdgcn_mfma_f32_16x16x32_f16(a1[ks], B1[ks], acc1, 0, 0, 0);
      acc2 = __builtin_amdgcn_mfma_f32_16x16x32_f16(a1[ks], B2[ks], acc2, 0, 0, 0);
      acc3 = __builtin_amdgcn_mfma_f32_16x16x32_f16(a2[ks], B3[ks], acc3, 0, 0, 0);
    }

    // h1[i] and h2[i-1]; C layout: col = n (lane&15), row = rb + j
    wh(h1w, rb + 0, n, fast_tanh(acc1[0]));
    wh(h1w, rb + 1, n, fast_tanh(acc1[1]));
    wh(h1w, rb + 2, n, fast_tanh(acc1[2]));
    wh(h1w, rb + 3, n, fast_tanh(acc1[3]));
    wh(h2w, rb + 0, n, fast_tanh(acc2[0] + acc3[0]));
    wh(h2w, rb + 1, n, fast_tanh(acc2[1] + acc3[1]));
    wh(h2w, rb + 2, n, fast_tanh(acc2[2] + acc3[2]));
    wh(h2w, rb + 3, n, fast_tanh(acc2[3] + acc3[3]));
    bar();                                // raw lgkm-only barrier
    xpc0 = nx0; xpc1 = nx1; xpc2 = nx2; xpc3 = nx3;
  }

  // peel i = T: h2[T-1] = tanh(bias2 + W_ih2.h1[T-1] + W_hh2.h2[T-2])
  {
    const char* h1p = h1s[1];             // h1[T-1]
    const char* h2p = h2s[0];             // h2[T-2]
    char* h2w = h2s[1];                   // h2[T-1]
    f16x8v a1[4], a2[4];
#pragma unroll
    for (int ks = 0; ks < 4; ++ks) {
      const int off = (lc * 256 + ks * 64 + lk * 16) ^ ((lc & 7) << 4);
      a1[ks] = *(const f16x8v*)(h1p + off);
      a2[ks] = *(const f16x8v*)(h2p + off);
    }
    f32x4 acc2 = {bias2, bias2, bias2, bias2};
    f32x4 acc3 = {0.f, 0.f, 0.f, 0.f};
#pragma unroll
    for (int ks = 0; ks < 4; ++ks) {
      acc2 = __builtin_amdgcn_mfma_f32_16x16x32_f16(a1[ks], B2[ks], acc2, 0, 0, 0);
      acc3 = __builtin_amdgcn_mfma_f32_16x16x32_f16(a2[ks], B3[ks], acc3, 0, 0, 0);
    }
    wh(h2w, rb + 0, n, fast_tanh(acc2[0] + acc3[0]));
    wh(h2w, rb + 1, n, fast_tanh(acc2[1] + acc3[1]));
    wh(h2w, rb + 2, n, fast_tanh(acc2[2] + acc3[2]));
    wh(h2w, rb + 3, n, fast_tanh(acc2[3] + acc3[3]));
    bar();
  }

  // projection + LayerNorm: thread (bl = t>>5, pp = t&31) does p = pp, pp+32
  {
    const int bl = t >> 5;        // batch within tile, 0..15
    const int pp = t & 31;
    const char* hf = h2s[1];
    float z0 = b_proj[pp], z1 = b_proj[pp + 32];
#pragma unroll
    for (int kc = 0; kc < 16; ++kc) {
      f16x8v hv = *(const f16x8v*)(hf + ((bl * 256 + kc * 16) ^ ((bl & 7) << 4)));
      float4 wa0 = *(const float4*)&W_proj[pp * H + kc * 8];
      float4 wb0 = *(const float4*)&W_proj[pp * H + kc * 8 + 4];
      float4 wa1 = *(const float4*)&W_proj[(pp + 32) * H + kc * 8];
      float4 wb1 = *(const float4*)&W_proj[(pp + 32) * H + kc * 8 + 4];
      z0 = fmaf(wa0.x, (float)hv[0], z0); z0 = fmaf(wa0.y, (float)hv[1], z0);
      z0 = fmaf(wa0.z, (float)hv[2], z0); z0 = fmaf(wa0.w, (float)hv[3], z0);
      z0 = fmaf(wb0.x, (float)hv[4], z0); z0 = fmaf(wb0.y, (float)hv[5], z0);
      z0 = fmaf(wb0.z, (float)hv[6], z0); z0 = fmaf(wb0.w, (float)hv[7], z0);
      z1 = fmaf(wa1.x, (float)hv[0], z1); z1 = fmaf(wa1.y, (float)hv[1], z1);
      z1 = fmaf(wa1.z, (float)hv[2], z1); z1 = fmaf(wa1.w, (float)hv[3], z1);
      z1 = fmaf(wb1.x, (float)hv[4], z1); z1 = fmaf(wb1.y, (float)hv[5], z1);
      z1 = fmaf(wb1.z, (float)hv[6], z1); z1 = fmaf(wb1.w, (float)hv[7], z1);
    }
    // LN over the 64 z-values of batch bl (32 lanes x 2 each; xor<32 stays
    // within the aligned 32-lane group)
    float s = z0 + z1;
#pragma unroll
    for (int d = 1; d < 32; d <<= 1) s += __shfl_xor(s, d);
    float mu = s * 0.015625f;
    float d0 = z0 - mu, d1 = z1 - mu;
    float v = d0 * d0 + d1 * d1;
#pragma unroll
    for (int d = 1; d < 32; d <<= 1) v += __shfl_xor(v, d);
    float rstd = rsqrtf(v * 0.015625f + 1e-5f);
    out[(bq + bl) * PROJ + pp]      = d0 * rstd * gamma[pp] + beta[pp];
    out[(bq + bl) * PROJ + pp + 32] = d1 * rstd * gamma[pp + 32] + beta[pp + 32];
  }
}

extern "C" void kernel_launch(void* const* d_in, const int* in_sizes, int n_in,
                              void* d_out, int out_size, void* d_ws, size_t ws_size,
                              hipStream_t stream) {
  const float* x      = (const float*)d_in[0];
  const float* W_ih1  = (const float*)d_in[1];
  const float* W_hh1  = (const float*)d_in[2];
  const float* b_ih1  = (const float*)d_in[3];
  const float* b_hh1  = (const float*)d_in[4];
  const float* W_ih2  = (const float*)d_in[5];
  const float* W_hh2  = (const float*)d_in[6];
  const float* b_ih2  = (const float*)d_in[7];
  const float* b_hh2  = (const float*)d_in[8];
  const float* W_proj = (const float*)d_in[9];
  const float* b_proj = (const float*)d_in[10];
  const float* gamma  = (const float*)d_in[11];
  const float* beta   = (const float*)d_in[12];

  float* xp1 = (float*)d_ws;   // BT*H*4 = 16 MB scratch

  xp1_gemm<<<BT / BM, 512, 0, stream>>>(x, W_ih1, b_ih1, b_hh1, xp1);
  rnn_fused<<<NBLK, 512, 0, stream>>>(xp1, W_hh1, W_ih2, W_hh2, b_ih2, b_hh2,
                                      W_proj, b_proj, gamma, beta,
                                      (float*)d_out);
}

// Round 12
// 397.423 us; speedup vs baseline: 1.6753x; 1.6753x over previous
//
#include <hip/hip_runtime.h>
#include <math.h>

#define H 128
#define IN 2048
#define PROJ 64
#define BT 32768      // B*T rows of x
#define T_STEPS 512
#define BATCH 64
#define BM 128
#define BKA 64

using f32x4  = __attribute__((ext_vector_type(4))) float;
using bfrag  = __attribute__((ext_vector_type(8))) short;   // 8 bf16
using h2_t   = __attribute__((ext_vector_type(2))) _Float16;

// v_cvt_pk_bf16_f32: d.lo = bf16(lo), d.hi = bf16(hi)  (RNE)
__device__ __forceinline__ unsigned cvtpk(float lo, float hi) {
  unsigned r;
  asm("v_cvt_pk_bf16_f32 %0, %1, %2" : "=v"(r) : "v"(lo), "v"(hi));
  return r;
}

// ---------------------------------------------------------------------------
// Kernel A: xp1[BT][H] = x[BT][IN] @ W_ih1^T + (b_ih1+b_hh1), bf16 MFMA.
// UNCHANGED (~60 us, near HBM floor).
// ---------------------------------------------------------------------------
__global__ __launch_bounds__(512) void xp1_gemm(
    const float* __restrict__ x, const float* __restrict__ W,
    const float* __restrict__ b1, const float* __restrict__ b2,
    float* __restrict__ xp1) {
  __shared__ __align__(16) char As[2][BM * BKA * 2];   // 2 x 16 KB
  __shared__ __align__(16) char Bs[2][H * BKA * 2];    // 2 x 16 KB
  const int t  = threadIdx.x;
  const int m0 = blockIdx.x * BM;
  const int wv = t >> 6, l = t & 63;
  const int wm = wv >> 2;
  const int wn = wv & 3;
  const int lr = l & 15;
  const int lq = l >> 4;

  const float* xg[4];
  const float* wg[4];
  int so[4];
#pragma unroll
  for (int i = 0; i < 4; ++i) {
    int c = t + 512 * i, r = c >> 4, k4 = c & 15;
    xg[i] = x + (size_t)(m0 + r) * IN + k4 * 4;
    wg[i] = W + (size_t)r * IN + k4 * 4;
    so[i] = (r * 128 + k4 * 8) ^ ((r & 7) << 4);
  }
  int ao[2][4], bo[2][2];
#pragma unroll
  for (int kf = 0; kf < 2; ++kf) {
#pragma unroll
    for (int mf = 0; mf < 4; ++mf) {
      int r = wm * 64 + mf * 16 + lr;
      ao[kf][mf] = (r * 128 + kf * 64 + lq * 16) ^ ((r & 7) << 4);
    }
#pragma unroll
    for (int nf = 0; nf < 2; ++nf) {
      int r = wn * 32 + nf * 16 + lr;
      bo[kf][nf] = (r * 128 + kf * 64 + lq * 16) ^ ((r & 7) << 4);
    }
  }

  f32x4 acc[4][2];
#pragma unroll
  for (int mf = 0; mf < 4; ++mf)
#pragma unroll
    for (int nf = 0; nf < 2; ++nf)
#pragma unroll
      for (int j = 0; j < 4; ++j) acc[mf][nf][j] = 0.f;

  float4 xr[4], wr[4];
#pragma unroll
  for (int i = 0; i < 4; ++i) {
    xr[i] = *(const float4*)&xg[i][0];
    wr[i] = *(const float4*)&wg[i][0];
  }
#pragma unroll
  for (int i = 0; i < 4; ++i) {
    uint2 ux; ux.x = cvtpk(xr[i].x, xr[i].y); ux.y = cvtpk(xr[i].z, xr[i].w);
    *(uint2*)(As[0] + so[i]) = ux;
    uint2 uw; uw.x = cvtpk(wr[i].x, wr[i].y); uw.y = cvtpk(wr[i].z, wr[i].w);
    *(uint2*)(Bs[0] + so[i]) = uw;
  }
  __syncthreads();

  for (int tc = 0; tc < 32; ++tc) {
    const int kc = (tc + 1) * BKA;
    if (tc < 31) {
#pragma unroll
      for (int i = 0; i < 4; ++i) {
        xr[i] = *(const float4*)&xg[i][kc];
        wr[i] = *(const float4*)&wg[i][kc];
      }
    }
    const char* Ab = As[tc & 1];
    const char* Bb = Bs[tc & 1];
#pragma unroll
    for (int kf = 0; kf < 2; ++kf) {
      bfrag af[4], bf[2];
#pragma unroll
      for (int mf = 0; mf < 4; ++mf) af[mf] = *(const bfrag*)(Ab + ao[kf][mf]);
#pragma unroll
      for (int nf = 0; nf < 2; ++nf) bf[nf] = *(const bfrag*)(Bb + bo[kf][nf]);
#pragma unroll
      for (int mf = 0; mf < 4; ++mf)
#pragma unroll
        for (int nf = 0; nf < 2; ++nf)
          acc[mf][nf] = __builtin_amdgcn_mfma_f32_16x16x32_bf16(
              af[mf], bf[nf], acc[mf][nf], 0, 0, 0);
    }
    if (tc < 31) {
      char* Aw = As[(tc + 1) & 1];
      char* Bw = Bs[(tc + 1) & 1];
#pragma unroll
      for (int i = 0; i < 4; ++i) {
        uint2 ux; ux.x = cvtpk(xr[i].x, xr[i].y); ux.y = cvtpk(xr[i].z, xr[i].w);
        *(uint2*)(Aw + so[i]) = ux;
        uint2 uw; uw.x = cvtpk(wr[i].x, wr[i].y); uw.y = cvtpk(wr[i].z, wr[i].w);
        *(uint2*)(Bw + so[i]) = uw;
      }
    }
    __syncthreads();
  }

  // epilogue: C/D layout col = lane&15, row = (lane>>4)*4 + j   [m89]
#pragma unroll
  for (int nf = 0; nf < 2; ++nf) {
    int n = wn * 32 + nf * 16 + lr;
    float bias = b1[n] + b2[n];
#pragma unroll
    for (int mf = 0; mf < 4; ++mf) {
      int mr = m0 + wm * 64 + mf * 16 + lq * 4;
#pragma unroll
      for (int j = 0; j < 4; ++j)
        xp1[(size_t)(mr + j) * H + n] = acc[mf][nf][j] + bias;
    }
  }
}

// ---------------------------------------------------------------------------
// Kernel B: fused 2-layer tanh RNN (best-measured R7 structure: skewed
// single-phase, 64 blocks x 512 thr, asm-resident f16 weights) plus:
//  - row-PAIR ownership r0=16w+2g, r1=r0+1 -> h writes are ONE packed
//    ds_write_b32 each (cvt pair), xp load is one dwordx2
//  - unroll-by-2: buffer parity compile-time, no pointer selects
//  - 2-deep xp prefetch (xc/xn/xf SSA rotation): load at step i first used
//    at step i+2 -> vmcnt wait provably off the critical path
// ---------------------------------------------------------------------------
struct Wrow { unsigned p0, p1, p2, p3, p4, p5, p6, p7; };  // 16 f16 = 8 h2

// issue-only, non-rematerializable 16B load
__device__ __forceinline__ float4 gld(const float* p) {
  float4 r;
  asm volatile("global_load_dwordx4 %0, %1, off" : "=v"(r) : "v"(p));
  return r;
}

__device__ __forceinline__ void waitv0() {
  asm volatile("s_waitcnt vmcnt(0)" ::: "memory");
  __builtin_amdgcn_sched_barrier(0);
}

// raw barrier: drain LDS ops only
__device__ __forceinline__ void bar() {
  asm volatile("s_waitcnt lgkmcnt(0)\n\ts_barrier" ::: "memory");
}

__device__ __forceinline__ unsigned pkh(float x, float y) {
  h2_t p = {(_Float16)x, (_Float16)y};
  return __builtin_bit_cast(unsigned, p);
}

__device__ __forceinline__ Wrow packrow(float4 a, float4 b, float4 c,
                                        float4 d) {
  Wrow w = {pkh(a.x, a.y), pkh(a.z, a.w), pkh(b.x, b.y), pkh(b.z, b.w),
            pkh(c.x, c.y), pkh(c.z, c.w), pkh(d.x, d.y), pkh(d.z, d.w)};
  return w;
}

__device__ __forceinline__ float d2(unsigned w, int h, float acc) {
  return __builtin_amdgcn_fdot2(__builtin_bit_cast(h2_t, w),
                                __builtin_bit_cast(h2_t, (unsigned)h), acc,
                                false);
}

__device__ __forceinline__ float dot16(Wrow w, int4 lo, int4 hi, float acc) {
  acc = d2(w.p0, lo.x, acc);
  acc = d2(w.p1, lo.y, acc);
  acc = d2(w.p2, lo.z, acc);
  acc = d2(w.p3, lo.w, acc);
  acc = d2(w.p4, hi.x, acc);
  acc = d2(w.p5, hi.y, acc);
  acc = d2(w.p6, hi.z, acc);
  acc = d2(w.p7, hi.w, acc);
  return acc;
}

template <int CTRL>
__device__ __forceinline__ float dpp_add(float x) {
  return x + __builtin_bit_cast(
                 float, __builtin_amdgcn_mov_dpp(__builtin_bit_cast(int, x),
                                                 CTRL, 0xf, 0xf, true));
}

__device__ __forceinline__ float red8(float v) {
  v = dpp_add<0xB1>(v);    // quad_perm [1,0,3,2]  (+ lane^1)
  v = dpp_add<0x4E>(v);    // quad_perm [2,3,0,1]  (+ lane^2)
  v = dpp_add<0x141>(v);   // row_half_mirror      (+ other quad of 8-group)
  return v;
}

__device__ __forceinline__ float fast_tanh(float x) {
  float e = __expf(2.0f * x);
  return 1.0f - 2.0f / (e + 1.0f);
}

__global__ __launch_bounds__(512)
__attribute__((amdgpu_waves_per_eu(1, 2)))
void rnn_fused(
    const float* __restrict__ xp1,
    const float* __restrict__ W_hh1, const float* __restrict__ W_ih2,
    const float* __restrict__ W_hh2, const float* __restrict__ b_ih2,
    const float* __restrict__ b_hh2, const float* __restrict__ W_proj,
    const float* __restrict__ b_proj, const float* __restrict__ gamma,
    const float* __restrict__ beta, float* __restrict__ out) {
  __shared__ __align__(16) _Float16 h1s[2][H];
  __shared__ __align__(16) _Float16 h2s[2][H];
  const int t = threadIdx.x;
  const int b = blockIdx.x;
  const int l = t & 63;
  const int w = t >> 6;
  const int g = (l >> 3) & 7;
  const int q = l & 7;
  const int r0 = 16 * w + 2 * g;    // row pair r0 (even), r0+1
  const int r1 = r0 + 1;

  // --- weight loads: issue-only asm + one wait (R6-proven residency) -------
  const float* pA = &W_hh1[r0 * H + 16 * q];
  const float* pB = &W_hh1[r1 * H + 16 * q];
  const float* pC = &W_ih2[r0 * H + 16 * q];
  const float* pD = &W_ih2[r1 * H + 16 * q];
  const float* pE = &W_hh2[r0 * H + 16 * q];
  const float* pF = &W_hh2[r1 * H + 16 * q];
  float4 A0 = gld(pA), A1 = gld(pA + 4), A2 = gld(pA + 8), A3 = gld(pA + 12);
  float4 B0 = gld(pB), B1 = gld(pB + 4), B2 = gld(pB + 8), B3 = gld(pB + 12);
  float4 C0 = gld(pC), C1 = gld(pC + 4), C2 = gld(pC + 8), C3 = gld(pC + 12);
  float4 D0 = gld(pD), D1 = gld(pD + 4), D2 = gld(pD + 8), D3 = gld(pD + 12);
  float4 E0 = gld(pE), E1 = gld(pE + 4), E2 = gld(pE + 8), E3 = gld(pE + 12);
  float4 F0 = gld(pF), F1 = gld(pF + 4), F2 = gld(pF + 8), F3 = gld(pF + 12);
  waitv0();

  Wrow W1r0 = packrow(A0, A1, A2, A3);
  Wrow W1r1 = packrow(B0, B1, B2, B3);
  Wrow W2r0 = packrow(C0, C1, C2, C3);
  Wrow W2r1 = packrow(D0, D1, D2, D3);
  Wrow W3r0 = packrow(E0, E1, E2, E3);
  Wrow W3r1 = packrow(F0, F1, F2, F3);

  const float bias2_0 = b_ih2[r0] + b_hh2[r0];
  const float bias2_1 = b_ih2[r1] + b_hh2[r1];

  // h1[-1], h2[-1] live in buffer parity (-1)&1 == 1
  if (t < H) { h1s[1][t] = (_Float16)0.f; h2s[1][t] = (_Float16)0.f; }
  __syncthreads();

  const float* xpr = xp1 + (size_t)b * T_STEPS * H + r0;  // pair base

  // peel i = 0: h1[0] = tanh(xp[0]); no h2 yet
  if (q == 0) {
    float2 x0 = *(const float2*)&xpr[0];
    *(unsigned*)&h1s[0][r0] = pkh(fast_tanh(x0.x), fast_tanh(x0.y));
  }
  __syncthreads();

  // 2-deep prefetch: xc for current step, xn for next
  float2 xc = *(const float2*)&xpr[1 * H];   // xp[1]
  float2 xn = *(const float2*)&xpr[2 * H];   // xp[2]

#define STEP(I, PAR)                                                         \
  {                                                                          \
    const _Float16* h1p = h1s[(PAR) ^ 1];   /* h1[I-1] */                    \
    const _Float16* h2p = h2s[(PAR)];       /* h2[I-2] */                    \
    _Float16* h1w = h1s[(PAR)];             /* h1[I]   */                    \
    _Float16* h2w = h2s[(PAR) ^ 1];         /* h2[I-1] */                    \
    float2 xf = float2{0.f, 0.f};                                            \
    if ((I) + 2 < T_STEPS) xf = *(const float2*)&xpr[(size_t)((I) + 2) * H]; \
    int4 l1 = *(const int4*)&h1p[16 * q];                                    \
    int4 u1 = *(const int4*)&h1p[16 * q + 8];                                \
    int4 l2 = *(const int4*)&h2p[16 * q];                                    \
    int4 u2 = *(const int4*)&h2p[16 * q + 8];                                \
    float a0 = dot16(W1r0, l1, u1, 0.f);                                     \
    float a1 = dot16(W1r1, l1, u1, 0.f);                                     \
    float c0 = dot16(W3r0, l2, u2, 0.f);                                     \
    float c1 = dot16(W3r1, l2, u2, 0.f);                                     \
    float bb0 = dot16(W2r0, l1, u1, c0);                                     \
    float bb1 = dot16(W2r1, l1, u1, c1);                                     \
    a0 = red8(a0); a1 = red8(a1);                                            \
    bb0 = red8(bb0); bb1 = red8(bb1);                                        \
    if (q == 0) {                                                            \
      *(unsigned*)&h1w[r0] =                                                 \
          pkh(fast_tanh(xc.x + a0), fast_tanh(xc.y + a1));                   \
      *(unsigned*)&h2w[r0] =                                                 \
          pkh(fast_tanh(bias2_0 + bb0), fast_tanh(bias2_1 + bb1));           \
    }                                                                        \
    bar();                                                                   \
    xc = xn; xn = xf;                                                        \
  }

  STEP(1, 1)
#pragma unroll 1
  for (int i = 2; i < T_STEPS; i += 2) {
    STEP(i, 0)
    STEP(i + 1, 1)
  }
#undef STEP

  // peel i = T: h2[T-1] = tanh(bias2 + W_ih2.h1[T-1] + W_hh2.h2[T-2])
  {
    const _Float16* h1p = h1s[1];           // h1[T-1]
    const _Float16* h2p = h2s[0];           // h2[T-2]
    _Float16* h2w = h2s[1];                 // h2[T-1]
    int4 l1 = *(const int4*)&h1p[16 * q];
    int4 u1 = *(const int4*)&h1p[16 * q + 8];
    int4 l2 = *(const int4*)&h2p[16 * q];
    int4 u2 = *(const int4*)&h2p[16 * q + 8];
    float c0 = dot16(W3r0, l2, u2, 0.f);
    float c1 = dot16(W3r1, l2, u2, 0.f);
    float bb0 = dot16(W2r0, l1, u1, c0);
    float bb1 = dot16(W2r1, l1, u1, c1);
    bb0 = red8(bb0); bb1 = red8(bb1);
    if (q == 0) {
      *(unsigned*)&h2w[r0] =
          pkh(fast_tanh(bias2_0 + bb0), fast_tanh(bias2_1 + bb1));
    }
    bar();
  }

  // projection + LayerNorm on h2s[1]; lanes 0..63 == wave 0 exactly
  if (t < PROJ) {
    const float* wp = W_proj + t * H;
    float z = b_proj[t];
#pragma unroll
    for (int i = 0; i < 32; ++i) {
      float4 wv = *(const float4*)&wp[4 * i];
      z = fmaf(wv.x, (float)h2s[1][4 * i + 0], z);
      z = fmaf(wv.y, (float)h2s[1][4 * i + 1], z);
      z = fmaf(wv.z, (float)h2s[1][4 * i + 2], z);
      z = fmaf(wv.w, (float)h2s[1][4 * i + 3], z);
    }
    float s = z;
#pragma unroll
    for (int d = 1; d < 64; d <<= 1) s += __shfl_xor(s, d);
    float mu = s * 0.015625f;
    float dz = z - mu;
    float v = dz * dz;
#pragma unroll
    for (int d = 1; d < 64; d <<= 1) v += __shfl_xor(v, d);
    float rstd = rsqrtf(v * 0.015625f + 1e-5f);
    out[b * PROJ + t] = dz * rstd * gamma[t] + beta[t];
  }
}

extern "C" void kernel_launch(void* const* d_in, const int* in_sizes, int n_in,
                              void* d_out, int out_size, void* d_ws, size_t ws_size,
                              hipStream_t stream) {
  const float* x      = (const float*)d_in[0];
  const float* W_ih1  = (const float*)d_in[1];
  const float* W_hh1  = (const float*)d_in[2];
  const float* b_ih1  = (const float*)d_in[3];
  const float* b_hh1  = (const float*)d_in[4];
  const float* W_ih2  = (const float*)d_in[5];
  const float* W_hh2  = (const float*)d_in[6];
  const float* b_ih2  = (const float*)d_in[7];
  const float* b_hh2  = (const float*)d_in[8];
  const float* W_proj = (const float*)d_in[9];
  const float* b_proj = (const float*)d_in[10];
  const float* gamma  = (const float*)d_in[11];
  const float* beta   = (const float*)d_in[12];

  float* xp1 = (float*)d_ws;   // BT*H*4 = 16 MB scratch

  xp1_gemm<<<BT / BM, 512, 0, stream>>>(x, W_ih1, b_ih1, b_hh1, xp1);
  rnn_fused<<<BATCH, 512, 0, stream>>>(xp1, W_hh1, W_ih2, W_hh2, b_ih2, b_hh2,
                                       W_proj, b_proj, gamma, beta,
                                       (float*)d_out);
}